// Round 13
// baseline (148.350 us; speedup 1.0000x reference)
//
#include <hip/hip_runtime.h>
#include <stdint.h>

// B=1, R=128, L=256, IN=128, DM=32, DIM=128
// out[i,j,k] = x[i,j,k] + (1/R)*sum_{r,c,d} mp[r,j,c]*mp[r,i,d]*W2[k,c*32+d] + b2[k]
// mp[r,i,d]  = sum_e m[r,i,e]*W1[d,e] + b1[d]
//
// mpF[rt][kr][lane][j]  rt=(i*32+d)>>4 (512), kr=r>>5 (4):
//     value mp[r = kr*32 + (lane>>4)*8 + j][row = rt*16 + (lane&15)]
// W2f[nt][kc][lane][j]  nt=kout>>4 (8), kc=d (32):
//     value W2t[kout=nt*16+(lane&15)][cd' = kc*32 + (lane>>4)*8 + j]
//
// FINAL LEDGER: r0=58. r2=62 (B from L2). r1/r3/r4 SPILLED. r5=53 (glds
// Bs). r6=52.6 (setprio null, kept). r7=68 (dual W2f streams spill; rule:
// ONE 8-deep wv[8]). r9=62.6 (barrier count NULL). r10=52.6 BEST (direct
// epilogue neutral, conflicts -260K). r11=253 (32x32x16 single-chain stepC
// -> scheduler hoist -> 720MB scratch; rule: >=2 indep acc chains).
// r12=52.0-52.6 (clean r10 restore).
// REGISTER BUDGET: 60 VGPR + 48 AGPR of 128/wave at 4 waves/SIMD; ~20
// slack. 2 blocks/CU in every healthy config. Plateau is latency-bound
// (MfmaUtil 26 / VALU 20 / HBM 14 / LDS ~50%), not a counter roofline.
//
// THIS ROUND (r13): wpre hoisted PRE-barrier in phases p1/p2/p3 (p0 was
// already pre-barrier). wv is dead from each stepC's end to the next wpre,
// and wpre reads only L2 — so the 8-fragment reload (~250 cyc) hides under
// the barrier drain instead of sitting on stepC's critical path. Register-
// neutral (wv statically allocated; live-range extension displaces only a
// few gwrite temps).

typedef __attribute__((ext_vector_type(8))) short bf16x8;
typedef __attribute__((ext_vector_type(4))) float f32x4;

#define MFMA16 __builtin_amdgcn_mfma_f32_16x16x32_bf16

__device__ __forceinline__ unsigned short f2bf(float f) {
    union { float f; unsigned int u; } x; x.f = f;
    unsigned int r = (x.u + 0x7fffu + ((x.u >> 16) & 1u)) >> 16;  // RNE
    return (unsigned short)r;
}

__device__ __forceinline__ bf16x8 load8f_bf(const float* p) {
    float4 v0 = *(const float4*)p;
    float4 v1 = *(const float4*)(p + 4);
    union { bf16x8 v; unsigned short u[8]; } r;
    r.u[0] = f2bf(v0.x); r.u[1] = f2bf(v0.y); r.u[2] = f2bf(v0.z); r.u[3] = f2bf(v0.w);
    r.u[4] = f2bf(v1.x); r.u[5] = f2bf(v1.y); r.u[6] = f2bf(v1.z); r.u[7] = f2bf(v1.w);
    return r.v;
}

// ---------------------------------------------------------------------------
// prep: blocks 0..511 -> mp GEMM -> mpF; blocks 512..575 -> W2 -> W2f
// ---------------------------------------------------------------------------
__global__ __launch_bounds__(256) void prep_kernel(
    const float* __restrict__ m, const float* __restrict__ W1,
    const float* __restrict__ pb1, const float* __restrict__ W2,
    unsigned short* __restrict__ mpF, unsigned short* __restrict__ W2f)
{
    const int bx = blockIdx.x;
    if (bx >= 512) {
        const int t    = (bx - 512) * 256 + threadIdx.x;   // 0..16383
        const int nt   = t >> 11;
        const int kc   = (t >> 6) & 31;
        const int lane = t & 63;
        const int ln   = lane & 15, q = lane >> 4;
        const float* src = W2 + (size_t)(nt * 16 + ln) * 1024 + kc;
        union { bf16x8 v; unsigned short u[8]; } r;
        #pragma unroll
        for (int j = 0; j < 8; ++j)
            r.u[j] = f2bf(src[(q * 8 + j) * 32]);
        *(bf16x8*)(W2f + (size_t)t * 8) = r.v;
        return;
    }
    const int lane = threadIdx.x & 63;
    const int w    = threadIdx.x >> 6;
    const int ln   = lane & 15, q = lane >> 4;
    const int tile = bx * 4 + w;          // 0..2047
    const int i    = tile >> 3;           // 0..255
    const int r0   = (tile & 7) * 16;     // r-tile base

    const float* Ap  = m  + ((size_t)(r0 + ln) * 256 + i) * 128 + q * 8;
    const float* Bp0 = W1 + (size_t)ln * 128 + q * 8;
    const float* Bp1 = W1 + (size_t)(16 + ln) * 128 + q * 8;

    f32x4 acc0 = {0.f, 0.f, 0.f, 0.f};
    f32x4 acc1 = {0.f, 0.f, 0.f, 0.f};
    #pragma unroll
    for (int ke = 0; ke < 4; ++ke) {
        bf16x8 a  = load8f_bf(Ap  + ke * 32);
        bf16x8 b0 = load8f_bf(Bp0 + ke * 32);
        bf16x8 b1 = load8f_bf(Bp1 + ke * 32);
        acc0 = MFMA16(a, b0, acc0, 0, 0, 0);
        acc1 = MFMA16(a, b1, acc1, 0, 0, 0);
    }
    const float bb0 = pb1[ln];
    const float bb1 = pb1[16 + ln];
    const int kr = r0 >> 5;
    const int qr = ((r0 >> 4) & 1) * 2 + (q >> 1);
    const int j0 = (q & 1) * 4;
    const size_t off0 = (size_t)(i * 2 + 0) * 2048 + kr * 512 + (qr * 16 + ln) * 8 + j0;
    const size_t off1 = (size_t)(i * 2 + 1) * 2048 + kr * 512 + (qr * 16 + ln) * 8 + j0;
    ushort4 o0, o1;
    o0.x = f2bf(acc0[0] + bb0); o0.y = f2bf(acc0[1] + bb0);
    o0.z = f2bf(acc0[2] + bb0); o0.w = f2bf(acc0[3] + bb0);
    o1.x = f2bf(acc1[0] + bb1); o1.y = f2bf(acc1[1] + bb1);
    o1.z = f2bf(acc1[2] + bb1); o1.w = f2bf(acc1[3] + bb1);
    *(ushort4*)(mpF + off0) = o0;
    *(ushort4*)(mpF + off1) = o1;
}

// ---------------------------------------------------------------------------
// fused helpers
// ---------------------------------------------------------------------------
// Direct global->LDS staging of one d-half of the block's 8 i-rows into Bs.
// Chunk cid = r*512 + tid is linear in tid, so LDS byte offset cid*16 is
// wave-uniform base + lane*16 (the HW requirement for global_load_lds).
__device__ __forceinline__ void stage_lds(const unsigned short* __restrict__ mpF,
                                          unsigned short* __restrict__ Bs,
                                          int i0, int dhalf, int tid)
{
    #pragma unroll
    for (int r = 0; r < 4; ++r) {
        const int cid = r * 512 + tid;            // 0..2047 (16B chunks)
        const int it  = cid >> 8;                 // i-slot 0..7
        const int pos = cid & 255;                // 16B unit within 4KB row
        const unsigned short* src =
            mpF + (size_t)((i0 + it) * 2 + dhalf) * 2048 + pos * 8;
        __builtin_amdgcn_global_load_lds(
            (const __attribute__((address_space(1))) unsigned int*)src,
            (__attribute__((address_space(3))) unsigned int*)(Bs + (size_t)cid * 8),
            16, 0, 0);
    }
}

__device__ __forceinline__ void stepB(const unsigned short* __restrict__ Ab,
                                      const unsigned short* __restrict__ Bs,
                                      int wn, int lane, f32x4 (&acc)[2][4])
{
    #pragma unroll
    for (int a = 0; a < 2; ++a)
        #pragma unroll
        for (int b = 0; b < 4; ++b)
            acc[a][b] = (f32x4){0.f, 0.f, 0.f, 0.f};
    #pragma unroll
    for (int ks = 0; ks < 4; ++ks) {
        bf16x8 av[2], bv[4];
        av[0] = *(const bf16x8*)(Ab + ks * 512);
        av[1] = *(const bf16x8*)(Ab + 2048 + ks * 512);
        #pragma unroll
        for (int bn = 0; bn < 4; ++bn)
            bv[bn] = *(const bf16x8*)(Bs + (wn * 4 + bn) * 2048 + ks * 512 + lane * 8);
        __builtin_amdgcn_s_setprio(1);
        #pragma unroll
        for (int am = 0; am < 2; ++am)
            #pragma unroll
            for (int bn = 0; bn < 4; ++bn)
                acc[am][bn] = MFMA16(av[am], bv[bn], acc[am][bn], 0, 0, 0);
        __builtin_amdgcn_s_setprio(0);
    }
}

__device__ __forceinline__ void gwrite(unsigned short* __restrict__ Gl,
                                       const f32x4 (&acc)[2][4],
                                       int ln, int q, int wm, int wn)
{
    #pragma unroll
    for (int am = 0; am < 2; ++am) {
        const int chunk = ln * 4 + am * 2 + (q >> 1);
        const int sig   = chunk >> 3;
        const int hbase = chunk * 256 + (q & 1) * 4;
        #pragma unroll
        for (int bn = 0; bn < 4; ++bn) {
            const int p  = (wn * 4 + bn) * 4 + wm;
            const int pp = p ^ sig;
            ushort4 g;
            g.x = f2bf(acc[am][bn][0]); g.y = f2bf(acc[am][bn][1]);
            g.z = f2bf(acc[am][bn][2]); g.w = f2bf(acc[am][bn][3]);
            *(ushort4*)(Gl + hbase + pp * 8) = g;
        }
    }
}

__device__ __forceinline__ void wpre(const unsigned short* __restrict__ wp, bf16x8 (&wv)[8])
{
    #pragma unroll
    for (int k8 = 0; k8 < 8; ++k8)
        wv[k8] = *(const bf16x8*)(wp + k8 * 512);
}

__device__ __forceinline__ void stepC(const unsigned short* __restrict__ Gl,
                                      const unsigned short* __restrict__ wp,
                                      bf16x8 (&wv)[8], int ln, int q,
                                      f32x4& c0, f32x4& c1)
{
    #pragma unroll
    for (int ks = 0; ks < 16; ++ks) {
        bf16x8 cur = wv[ks & 7];
        if (ks < 8) wv[ks & 7] = *(const bf16x8*)(wp + (ks + 8) * 512);
        const int chunk = ks * 4 + q;
        const int sig   = chunk >> 3;
        const unsigned short* gp = Gl + chunk * 256 + ((ln ^ sig) << 3);
        bf16x8 ag0 = *(const bf16x8*)gp;          // pairs 0..15
        bf16x8 ag1 = *(const bf16x8*)(gp + 128);  // pairs 16..31
        __builtin_amdgcn_s_setprio(1);
        c0 = MFMA16(ag0, cur, c0, 0, 0, 0);
        c1 = MFMA16(ag1, cur, c1, 0, 0, 0);
        __builtin_amdgcn_s_setprio(0);
    }
}

// ---------------------------------------------------------------------------
// fused: block = 8i x 8j (64 pairs), 2 d-halves x 2 j-halves.
// r10 schedule + wpre hoisted pre-barrier (p1/p2/p3); direct epilogue.
// ---------------------------------------------------------------------------
__global__ __launch_bounds__(512, 4) void fused_kernel(
    const float* __restrict__ x, const float* __restrict__ b2,
    const unsigned short* __restrict__ mpF, const unsigned short* __restrict__ W2f,
    float* __restrict__ out)
{
    __shared__ __align__(16) unsigned char smem[65536];
    unsigned short* Gl = (unsigned short*)smem;            // 64 chunks x 256 shorts
    unsigned short* Bs = (unsigned short*)(smem + 32768);  // 8 i x 2048 shorts

    const int tid  = threadIdx.x;
    const int lane = tid & 63, w = tid >> 6;
    const int ln   = lane & 15, q = lane >> 4;
    const int wm   = w & 3, wn = w >> 2;

    const int i0 = blockIdx.x * 8;            // gridDim.x = 32
    const int j0 = blockIdx.y * 8;            // gridDim.y = 32

    const unsigned short* Ab0 = mpF + (size_t)((j0 + wm) * 2) * 2048 + lane * 8;
    const unsigned short* Ab1 = Ab0 + 16384;                   // +4 j rows
    const unsigned short* wp0 = W2f + (size_t)(w * 32) * 512 + lane * 8;
    const unsigned short* wp1 = wp0 + 16 * 512;

    f32x4 cacc[4];
    #pragma unroll
    for (int t = 0; t < 4; ++t) cacc[t] = (f32x4){0.f, 0.f, 0.f, 0.f};
    f32x4 acc[2][4];
    bf16x8 wv[8];

    // ---- stage Bs(d0): direct global->LDS, drained by the barrier ----
    stage_lds(mpF, Bs, i0, 0, tid);
    __syncthreads();                                   // Bs(d0) ready

    // ---- (j0, d0) ----
    stepB(Ab0, Bs, wn, lane, acc);
    wpre(wp0, wv);                                     // pre-barrier (as in r10)
    gwrite(Gl, acc, ln, q, wm, wn);
    __syncthreads();                                   // Gl(j0,d0) ready
    stepC(Gl, wp0, wv, ln, q, cacc[0], cacc[1]);

    // ---- (j1, d0): stepB early (regs only); wpre hoisted pre-barrier ----
    stepB(Ab1, Bs, wn, lane, acc);
    wpre(wp0, wv);                                     // hoisted: hides under barrier
    __syncthreads();                                   // Gl(j0,d0) reads done
    gwrite(Gl, acc, ln, q, wm, wn);
    __syncthreads();                                   // Gl(j1,d0) ready; Bs(d0) dead
    stage_lds(mpF, Bs, i0, 1, tid);                    // d1 staging lands during stepC
    stepC(Gl, wp0, wv, ln, q, cacc[2], cacc[3]);
    wpre(wp1, wv);                                     // hoisted: hides under barrier
    __syncthreads();                                   // Bs(d1) ready + Gl reads done

    // ---- (j0, d1) ----
    stepB(Ab0, Bs, wn, lane, acc);
    gwrite(Gl, acc, ln, q, wm, wn);
    __syncthreads();                                   // Gl(j0,d1) ready
    stepC(Gl, wp1, wv, ln, q, cacc[0], cacc[1]);

    // ---- (j1, d1): stepB early; wpre hoisted pre-barrier ----
    stepB(Ab1, Bs, wn, lane, acc);
    wpre(wp1, wv);                                     // hoisted: hides under barrier
    __syncthreads();                                   // Gl(j0,d1) reads done
    gwrite(Gl, acc, ln, q, wm, wn);
    __syncthreads();                                   // Gl(j1,d1) ready

    // prefetch x values for this wave's 16 output cells (overlap stepC p3)
    const int kk = w * 16 + ln;
    const float bb = b2[kk];
    float xv16[16];
    #pragma unroll
    for (int jh = 0; jh < 2; ++jh)
        #pragma unroll
        for (int pt = 0; pt < 2; ++pt)
            #pragma unroll
            for (int rg = 0; rg < 4; ++rg) {
                const size_t addr =
                    ((size_t)(i0 + pt * 4 + q) * 256 + (j0 + jh * 4 + rg)) * 128 + kk;
                xv16[(jh * 2 + pt) * 4 + rg] = x[addr];
            }

    stepC(Gl, wp1, wv, ln, q, cacc[2], cacc[3]);

    // ---- direct epilogue: store from cacc, no LDS, no barrier ----
    const float invR = 1.0f / 128.0f;
    #pragma unroll
    for (int jh = 0; jh < 2; ++jh)
        #pragma unroll
        for (int pt = 0; pt < 2; ++pt)
            #pragma unroll
            for (int rg = 0; rg < 4; ++rg) {
                const size_t addr =
                    ((size_t)(i0 + pt * 4 + q) * 256 + (j0 + jh * 4 + rg)) * 128 + kk;
                out[addr] = xv16[(jh * 2 + pt) * 4 + rg]
                          + cacc[jh * 2 + pt][rg] * invR + bb;
            }
}

extern "C" void kernel_launch(void* const* d_in, const int* in_sizes, int n_in,
                              void* d_out, int out_size, void* d_ws, size_t ws_size,
                              hipStream_t stream) {
    const float* x  = (const float*)d_in[0];
    const float* m  = (const float*)d_in[1];
    const float* W1 = (const float*)d_in[2];
    const float* b1 = (const float*)d_in[3];
    const float* W2 = (const float*)d_in[4];
    const float* b2 = (const float*)d_in[5];
    float* out = (float*)d_out;

    unsigned short* mpF = (unsigned short*)d_ws;               // 512*2048 h = 2 MB
    unsigned short* W2f = mpF + (size_t)512 * 2048;            // 131072 h = 256 KB

    prep_kernel<<<dim3(576), dim3(256), 0, stream>>>(m, W1, b1, W2, mpF, W2f);
    fused_kernel<<<dim3(32, 32), dim3(512), 0, stream>>>(x, b2, mpF, W2f, out);
}

// Round 14
// 137.820 us; speedup vs baseline: 1.0764x; 1.0764x over previous
//
#include <hip/hip_runtime.h>
#include <stdint.h>

// B=1, R=128, L=256, IN=128, DM=32, DIM=128
// out[i,j,k] = x[i,j,k] + (1/R)*sum_{r,c,d} mp[r,j,c]*mp[r,i,d]*W2[k,c*32+d] + b2[k]
// mp[r,i,d]  = sum_e m[r,i,e]*W1[d,e] + b1[d]
//
// mpF[rt][kr][lane][j]  rt=(i*32+d)>>4 (512), kr=r>>5 (4):
//     value mp[r = kr*32 + (lane>>4)*8 + j][row = rt*16 + (lane&15)]
// W2f[nt][kc][lane][j]  nt=kout>>4 (8), kc=d (32):
//     value W2t[kout=nt*16+(lane&15)][cd' = kc*32 + (lane>>4)*8 + j]
//
// FINAL LEDGER (13 rounds): r0=58. r2=62 (B from L2). r1/r3/r4 SPILLED.
// r5=53 (glds Bs, +67%-style win from global_load_lds width-16). r6=52.6
// (setprio null, kept). r7=68 (dual W2f streams spill; rule: ONE 8-deep
// wv[8]). r9=62.6 (barrier count NULL). r10=52.6 BEST (direct epilogue).
// r11=253 (32x32x16 single-chain stepC -> 720MB scratch; rule: >=2 indep
// acc chains). r12=52.0-52.6 (clean restore). r13=60.7 SPILLED (wpre hoist
// across barrier: WRITE +26MB; rule: NOTHING extra lives across a phase
// barrier — r10's wpre-after-barrier placement is register-minimal).
//
// REGISTER ENVELOPE: 60 VGPR + 48 AGPR of the 128/wave quantum at 4
// waves/SIMD; 2 blocks/CU in every healthy config. Plateau is latency/
// dependency-bound (MfmaUtil 26 / VALU 20 / HBM 14 / LDS ~50%), not a
// counter roofline. All register-feasible levers measured. This is the
// verified best (r10/r12), reproduced twice.

typedef __attribute__((ext_vector_type(8))) short bf16x8;
typedef __attribute__((ext_vector_type(4))) float f32x4;

#define MFMA16 __builtin_amdgcn_mfma_f32_16x16x32_bf16

__device__ __forceinline__ unsigned short f2bf(float f) {
    union { float f; unsigned int u; } x; x.f = f;
    unsigned int r = (x.u + 0x7fffu + ((x.u >> 16) & 1u)) >> 16;  // RNE
    return (unsigned short)r;
}

__device__ __forceinline__ bf16x8 load8f_bf(const float* p) {
    float4 v0 = *(const float4*)p;
    float4 v1 = *(const float4*)(p + 4);
    union { bf16x8 v; unsigned short u[8]; } r;
    r.u[0] = f2bf(v0.x); r.u[1] = f2bf(v0.y); r.u[2] = f2bf(v0.z); r.u[3] = f2bf(v0.w);
    r.u[4] = f2bf(v1.x); r.u[5] = f2bf(v1.y); r.u[6] = f2bf(v1.z); r.u[7] = f2bf(v1.w);
    return r.v;
}

// ---------------------------------------------------------------------------
// prep: blocks 0..511 -> mp GEMM -> mpF; blocks 512..575 -> W2 -> W2f
// ---------------------------------------------------------------------------
__global__ __launch_bounds__(256) void prep_kernel(
    const float* __restrict__ m, const float* __restrict__ W1,
    const float* __restrict__ pb1, const float* __restrict__ W2,
    unsigned short* __restrict__ mpF, unsigned short* __restrict__ W2f)
{
    const int bx = blockIdx.x;
    if (bx >= 512) {
        const int t    = (bx - 512) * 256 + threadIdx.x;   // 0..16383
        const int nt   = t >> 11;
        const int kc   = (t >> 6) & 31;
        const int lane = t & 63;
        const int ln   = lane & 15, q = lane >> 4;
        const float* src = W2 + (size_t)(nt * 16 + ln) * 1024 + kc;
        union { bf16x8 v; unsigned short u[8]; } r;
        #pragma unroll
        for (int j = 0; j < 8; ++j)
            r.u[j] = f2bf(src[(q * 8 + j) * 32]);
        *(bf16x8*)(W2f + (size_t)t * 8) = r.v;
        return;
    }
    const int lane = threadIdx.x & 63;
    const int w    = threadIdx.x >> 6;
    const int ln   = lane & 15, q = lane >> 4;
    const int tile = bx * 4 + w;          // 0..2047
    const int i    = tile >> 3;           // 0..255
    const int r0   = (tile & 7) * 16;     // r-tile base

    const float* Ap  = m  + ((size_t)(r0 + ln) * 256 + i) * 128 + q * 8;
    const float* Bp0 = W1 + (size_t)ln * 128 + q * 8;
    const float* Bp1 = W1 + (size_t)(16 + ln) * 128 + q * 8;

    f32x4 acc0 = {0.f, 0.f, 0.f, 0.f};
    f32x4 acc1 = {0.f, 0.f, 0.f, 0.f};
    #pragma unroll
    for (int ke = 0; ke < 4; ++ke) {
        bf16x8 a  = load8f_bf(Ap  + ke * 32);
        bf16x8 b0 = load8f_bf(Bp0 + ke * 32);
        bf16x8 b1 = load8f_bf(Bp1 + ke * 32);
        acc0 = MFMA16(a, b0, acc0, 0, 0, 0);
        acc1 = MFMA16(a, b1, acc1, 0, 0, 0);
    }
    const float bb0 = pb1[ln];
    const float bb1 = pb1[16 + ln];
    const int kr = r0 >> 5;
    const int qr = ((r0 >> 4) & 1) * 2 + (q >> 1);
    const int j0 = (q & 1) * 4;
    const size_t off0 = (size_t)(i * 2 + 0) * 2048 + kr * 512 + (qr * 16 + ln) * 8 + j0;
    const size_t off1 = (size_t)(i * 2 + 1) * 2048 + kr * 512 + (qr * 16 + ln) * 8 + j0;
    ushort4 o0, o1;
    o0.x = f2bf(acc0[0] + bb0); o0.y = f2bf(acc0[1] + bb0);
    o0.z = f2bf(acc0[2] + bb0); o0.w = f2bf(acc0[3] + bb0);
    o1.x = f2bf(acc1[0] + bb1); o1.y = f2bf(acc1[1] + bb1);
    o1.z = f2bf(acc1[2] + bb1); o1.w = f2bf(acc1[3] + bb1);
    *(ushort4*)(mpF + off0) = o0;
    *(ushort4*)(mpF + off1) = o1;
}

// ---------------------------------------------------------------------------
// fused helpers
// ---------------------------------------------------------------------------
// Direct global->LDS staging of one d-half of the block's 8 i-rows into Bs.
// Chunk cid = r*512 + tid is linear in tid, so LDS byte offset cid*16 is
// wave-uniform base + lane*16 (the HW requirement for global_load_lds).
__device__ __forceinline__ void stage_lds(const unsigned short* __restrict__ mpF,
                                          unsigned short* __restrict__ Bs,
                                          int i0, int dhalf, int tid)
{
    #pragma unroll
    for (int r = 0; r < 4; ++r) {
        const int cid = r * 512 + tid;            // 0..2047 (16B chunks)
        const int it  = cid >> 8;                 // i-slot 0..7
        const int pos = cid & 255;                // 16B unit within 4KB row
        const unsigned short* src =
            mpF + (size_t)((i0 + it) * 2 + dhalf) * 2048 + pos * 8;
        __builtin_amdgcn_global_load_lds(
            (const __attribute__((address_space(1))) unsigned int*)src,
            (__attribute__((address_space(3))) unsigned int*)(Bs + (size_t)cid * 8),
            16, 0, 0);
    }
}

__device__ __forceinline__ void stepB(const unsigned short* __restrict__ Ab,
                                      const unsigned short* __restrict__ Bs,
                                      int wn, int lane, f32x4 (&acc)[2][4])
{
    #pragma unroll
    for (int a = 0; a < 2; ++a)
        #pragma unroll
        for (int b = 0; b < 4; ++b)
            acc[a][b] = (f32x4){0.f, 0.f, 0.f, 0.f};
    #pragma unroll
    for (int ks = 0; ks < 4; ++ks) {
        bf16x8 av[2], bv[4];
        av[0] = *(const bf16x8*)(Ab + ks * 512);
        av[1] = *(const bf16x8*)(Ab + 2048 + ks * 512);
        #pragma unroll
        for (int bn = 0; bn < 4; ++bn)
            bv[bn] = *(const bf16x8*)(Bs + (wn * 4 + bn) * 2048 + ks * 512 + lane * 8);
        __builtin_amdgcn_s_setprio(1);
        #pragma unroll
        for (int am = 0; am < 2; ++am)
            #pragma unroll
            for (int bn = 0; bn < 4; ++bn)
                acc[am][bn] = MFMA16(av[am], bv[bn], acc[am][bn], 0, 0, 0);
        __builtin_amdgcn_s_setprio(0);
    }
}

__device__ __forceinline__ void gwrite(unsigned short* __restrict__ Gl,
                                       const f32x4 (&acc)[2][4],
                                       int ln, int q, int wm, int wn)
{
    #pragma unroll
    for (int am = 0; am < 2; ++am) {
        const int chunk = ln * 4 + am * 2 + (q >> 1);
        const int sig   = chunk >> 3;
        const int hbase = chunk * 256 + (q & 1) * 4;
        #pragma unroll
        for (int bn = 0; bn < 4; ++bn) {
            const int p  = (wn * 4 + bn) * 4 + wm;
            const int pp = p ^ sig;
            ushort4 g;
            g.x = f2bf(acc[am][bn][0]); g.y = f2bf(acc[am][bn][1]);
            g.z = f2bf(acc[am][bn][2]); g.w = f2bf(acc[am][bn][3]);
            *(ushort4*)(Gl + hbase + pp * 8) = g;
        }
    }
}

__device__ __forceinline__ void wpre(const unsigned short* __restrict__ wp, bf16x8 (&wv)[8])
{
    #pragma unroll
    for (int k8 = 0; k8 < 8; ++k8)
        wv[k8] = *(const bf16x8*)(wp + k8 * 512);
}

__device__ __forceinline__ void stepC(const unsigned short* __restrict__ Gl,
                                      const unsigned short* __restrict__ wp,
                                      bf16x8 (&wv)[8], int ln, int q,
                                      f32x4& c0, f32x4& c1)
{
    #pragma unroll
    for (int ks = 0; ks < 16; ++ks) {
        bf16x8 cur = wv[ks & 7];
        if (ks < 8) wv[ks & 7] = *(const bf16x8*)(wp + (ks + 8) * 512);
        const int chunk = ks * 4 + q;
        const int sig   = chunk >> 3;
        const unsigned short* gp = Gl + chunk * 256 + ((ln ^ sig) << 3);
        bf16x8 ag0 = *(const bf16x8*)gp;          // pairs 0..15
        bf16x8 ag1 = *(const bf16x8*)(gp + 128);  // pairs 16..31
        __builtin_amdgcn_s_setprio(1);
        c0 = MFMA16(ag0, cur, c0, 0, 0, 0);
        c1 = MFMA16(ag1, cur, c1, 0, 0, 0);
        __builtin_amdgcn_s_setprio(0);
    }
}

// ---------------------------------------------------------------------------
// fused: block = 8i x 8j (64 pairs), 2 d-halves x 2 j-halves.
// r6 schedule + direct epilogue (no Ep transpose, no trailing barriers).
// ---------------------------------------------------------------------------
__global__ __launch_bounds__(512, 4) void fused_kernel(
    const float* __restrict__ x, const float* __restrict__ b2,
    const unsigned short* __restrict__ mpF, const unsigned short* __restrict__ W2f,
    float* __restrict__ out)
{
    __shared__ __align__(16) unsigned char smem[65536];
    unsigned short* Gl = (unsigned short*)smem;            // 64 chunks x 256 shorts
    unsigned short* Bs = (unsigned short*)(smem + 32768);  // 8 i x 2048 shorts

    const int tid  = threadIdx.x;
    const int lane = tid & 63, w = tid >> 6;
    const int ln   = lane & 15, q = lane >> 4;
    const int wm   = w & 3, wn = w >> 2;

    const int i0 = blockIdx.x * 8;            // gridDim.x = 32
    const int j0 = blockIdx.y * 8;            // gridDim.y = 32

    const unsigned short* Ab0 = mpF + (size_t)((j0 + wm) * 2) * 2048 + lane * 8;
    const unsigned short* Ab1 = Ab0 + 16384;                   // +4 j rows
    const unsigned short* wp0 = W2f + (size_t)(w * 32) * 512 + lane * 8;
    const unsigned short* wp1 = wp0 + 16 * 512;

    f32x4 cacc[4];
    #pragma unroll
    for (int t = 0; t < 4; ++t) cacc[t] = (f32x4){0.f, 0.f, 0.f, 0.f};
    f32x4 acc[2][4];
    bf16x8 wv[8];

    // ---- stage Bs(d0): direct global->LDS, drained by the barrier ----
    stage_lds(mpF, Bs, i0, 0, tid);
    __syncthreads();                                   // Bs(d0) ready

    // ---- (j0, d0) ----
    stepB(Ab0, Bs, wn, lane, acc);
    wpre(wp0, wv);
    gwrite(Gl, acc, ln, q, wm, wn);
    __syncthreads();                                   // Gl(j0,d0) ready
    stepC(Gl, wp0, wv, ln, q, cacc[0], cacc[1]);

    // ---- (j1, d0): stepB early (regs only) ----
    stepB(Ab1, Bs, wn, lane, acc);
    __syncthreads();                                   // Gl(j0,d0) reads done
    wpre(wp0, wv);
    gwrite(Gl, acc, ln, q, wm, wn);
    __syncthreads();                                   // Gl(j1,d0) ready; Bs(d0) dead
    stage_lds(mpF, Bs, i0, 1, tid);                    // d1 staging lands during stepC
    stepC(Gl, wp0, wv, ln, q, cacc[2], cacc[3]);
    __syncthreads();                                   // Bs(d1) ready + Gl reads done

    // ---- (j0, d1) ----
    stepB(Ab0, Bs, wn, lane, acc);
    wpre(wp1, wv);
    gwrite(Gl, acc, ln, q, wm, wn);
    __syncthreads();                                   // Gl(j0,d1) ready
    stepC(Gl, wp1, wv, ln, q, cacc[0], cacc[1]);

    // ---- (j1, d1) ----
    stepB(Ab1, Bs, wn, lane, acc);
    __syncthreads();                                   // Gl(j0,d1) reads done
    wpre(wp1, wv);
    gwrite(Gl, acc, ln, q, wm, wn);
    __syncthreads();                                   // Gl(j1,d1) ready

    // prefetch x values for this wave's 16 output cells (overlap stepC p3)
    const int kk = w * 16 + ln;
    const float bb = b2[kk];
    float xv16[16];
    #pragma unroll
    for (int jh = 0; jh < 2; ++jh)
        #pragma unroll
        for (int pt = 0; pt < 2; ++pt)
            #pragma unroll
            for (int rg = 0; rg < 4; ++rg) {
                const size_t addr =
                    ((size_t)(i0 + pt * 4 + q) * 256 + (j0 + jh * 4 + rg)) * 128 + kk;
                xv16[(jh * 2 + pt) * 4 + rg] = x[addr];
            }

    stepC(Gl, wp1, wv, ln, q, cacc[2], cacc[3]);

    // ---- direct epilogue: store from cacc, no LDS, no barrier ----
    const float invR = 1.0f / 128.0f;
    #pragma unroll
    for (int jh = 0; jh < 2; ++jh)
        #pragma unroll
        for (int pt = 0; pt < 2; ++pt)
            #pragma unroll
            for (int rg = 0; rg < 4; ++rg) {
                const size_t addr =
                    ((size_t)(i0 + pt * 4 + q) * 256 + (j0 + jh * 4 + rg)) * 128 + kk;
                out[addr] = xv16[(jh * 2 + pt) * 4 + rg]
                          + cacc[jh * 2 + pt][rg] * invR + bb;
            }
}

extern "C" void kernel_launch(void* const* d_in, const int* in_sizes, int n_in,
                              void* d_out, int out_size, void* d_ws, size_t ws_size,
                              hipStream_t stream) {
    const float* x  = (const float*)d_in[0];
    const float* m  = (const float*)d_in[1];
    const float* W1 = (const float*)d_in[2];
    const float* b1 = (const float*)d_in[3];
    const float* W2 = (const float*)d_in[4];
    const float* b2 = (const float*)d_in[5];
    float* out = (float*)d_out;

    unsigned short* mpF = (unsigned short*)d_ws;               // 512*2048 h = 2 MB
    unsigned short* W2f = mpF + (size_t)512 * 2048;            // 131072 h = 256 KB

    prep_kernel<<<dim3(576), dim3(256), 0, stream>>>(m, W1, b1, W2, mpF, W2f);
    fused_kernel<<<dim3(32, 32), dim3(512), 0, stream>>>(x, b2, mpF, W2f, out);
}